// Round 1
// baseline (435.611 us; speedup 1.0000x reference)
//
#include <hip/hip_runtime.h>

// Problem constants (from reference): B=8192, K=512, C=16
#define B_SZ 8192
#define K_SZ 512
#define C_SZ 16

// R3: latency/occupancy attack on the run-length search.
//
// Previous version (R2): 1 thread per (b,c), 5-probe cacheline binary search
// + 1 line read = 6-deep dependent scattered-miss chain, and only 2048 waves
// total (2 waves/SIMD) -> latency-bound, ~95 us of the timed region.
//
// R3: 4 lanes per mask row, one 64-lane wave per example b (16 candidates x
// 4 lanes). Two dependent memory rounds instead of six:
//   Round 1: lanes j=0..3 probe row[j*128]; __ballot nibble -> quarter jmax
//            containing the 1->0 boundary (row[0]==1 guaranteed, p>=1).
//   Round 2: the 4 lanes read the 512B window [jmax*128, jmax*128+128) with
//            8 dwordx4 each (per-instruction each group covers one full 64B
//            line -> perfectly coalesced), sum it -> s = ones in window.
//   t = 128*jmax + s - 1.
// Waves: 2048 -> 8192 (4x TLP), chain 6 -> 2. We fetch ~100 MB instead of
// ~60 MB but in DRAM-friendly contiguous 512B chunks at far higher
// efficiency; the kernel moves from latency-bound toward BW-bound.
//
// Softmax over the 16 candidates is done wave-internally: each 4-lane group
// holds its candidate's adjusted logit (replicated), __shfl_xor offsets
// {4,8,16,32} reduce exactly once across the 16 groups.
__global__ __launch_bounds__(256) void rocloss_kernel(
    const float* __restrict__ logits,   // [B, K, C] f32
    const int*   __restrict__ target,   // [B] i32
    const int*   __restrict__ mask,     // [B, C, K] i32 (leading-ones rows)
    float*       __restrict__ out)      // [1] f32 (pre-zeroed)
{
    const int tid  = threadIdx.x;
    const int lane = tid & 63;
    const int wv   = tid >> 6;                 // wave within block, 0..3
    const int b    = blockIdx.x * 4 + wv;      // one wave per example
    const int c    = lane >> 2;                // candidate ending, 0..15
    const int j    = lane & 3;                 // sub-lane within 4-lane group

    const int* __restrict__ row = mask + (size_t)(b * C_SZ + c) * K_SZ;

    // ---- Round 1: probe elements {0,128,256,384} of this row ----
    const int probe = row[j << 7];
    const unsigned long long bal = __ballot(probe != 0);
    const int nib  = (int)((bal >> (c << 2)) & 0xfull);   // 4 bits, >=1
    const int jmax = 31 - __clz(nib);          // last quarter starting with 1

    // ---- Round 2: read the 128-elem (512 B) window, count the ones ----
    // Lane j reads int4s {j, j+4, ..., j+28}: each unrolled load has the
    // 4 lanes of a group covering one contiguous 64B line.
    const int4* __restrict__ w4 = (const int4*)(row + (jmax << 7));
    int s = 0;
    #pragma unroll
    for (int i = 0; i < 8; ++i) {
        const int4 q = w4[j + (i << 2)];
        s += q.x + q.y + q.z + q.w;
    }
    s += __shfl_xor(s, 1);
    s += __shfl_xor(s, 2);                     // all 4 lanes: ones in window
    const int t = (jmax << 7) + s - 1;         // counter = run_length - 1

    // ---- Gather the logit at the last valid timestep: logits[b][t][c] ----
    // (4 lanes of a group hit the same address -> single request, broadcast)
    const float a = logits[((size_t)b * K_SZ + (size_t)t) * C_SZ + c];

    // ---- log-softmax across the 16 candidate groups (offsets 4..32) ----
    float m = a;
    #pragma unroll
    for (int off = 32; off >= 4; off >>= 1)
        m = fmaxf(m, __shfl_xor(m, off));
    const float e = __expf(a - m);
    float s2 = e;
    #pragma unroll
    for (int off = 32; off >= 4; off >>= 1)
        s2 += __shfl_xor(s2, off);
    const float lse = m + __logf(s2);          // logsumexp over 16 candidates

    // ---- loss_b = lse - a[target[b]]; mean over B; one atomic per block ----
    __shared__ float acc;
    if (tid == 0) acc = 0.0f;
    __syncthreads();
    if (c == target[b] && j == 0)
        atomicAdd(&acc, lse - a);              // 4 LDS atomics per block
    __syncthreads();
    if (tid == 0)
        atomicAdd(out, acc * (1.0f / (float)B_SZ));
}

extern "C" void kernel_launch(void* const* d_in, const int* in_sizes, int n_in,
                              void* d_out, int out_size, void* d_ws, size_t ws_size,
                              hipStream_t stream) {
    const float* logits = (const float*)d_in[0];   // [B,K,C] f32
    const int*   target = (const int*)d_in[1];     // [B] i32
    const int*   mask   = (const int*)d_in[2];     // [B,C,K] i32
    float* out = (float*)d_out;

    // d_out is poisoned with 0xAA before every launch; zero it for the atomics.
    hipMemsetAsync(out, 0, sizeof(float), stream);

    // One wave per example: B/4 blocks of 256 threads = 8192 waves.
    rocloss_kernel<<<B_SZ / 4, 256, 0, stream>>>(logits, target, mask, out);
}